// Round 1
// baseline (72.821 us; speedup 1.0000x reference)
//
#include <hip/hip_runtime.h>

#define C_IN  32
#define C_OUT 64
#define HH    64
#define WW    64

// ---------------------------------------------------------------------------
// Weight-product precompute: Wt[p][ic][oc][12] (9 used + 3 pad)
// W~_k = Ew(k) * (w_k if (p+k) odd), Ew(k) = prod_{j>=k, (p+j) even} w_j
// ---------------------------------------------------------------------------
__global__ void wprod_kernel(const float* __restrict__ w, float* __restrict__ Wt) {
    int t = blockIdx.x * 256 + threadIdx.x;
    if (t >= 2 * C_IN * C_OUT) return;
    int oc = t & 63;
    int ic = (t >> 6) & 31;
    int p  = t >> 11;
    const float* wp = w + (oc * C_IN + ic) * 9;
    float W[9];
    float Ew = 1.f;
    #pragma unroll
    for (int k = 8; k >= 0; --k) {
        float wk = wp[k];
        if (((p + k) & 1) == 0) { Ew *= wk; W[k] = Ew; }
        else                    { W[k] = wk * Ew; }
    }
    float* dst = Wt + ((p * C_IN + ic) * C_OUT + oc) * 12;
    #pragma unroll
    for (int k = 0; k < 9; ++k) dst[k] = W[k];
    dst[9] = 0.f; dst[10] = 0.f; dst[11] = 0.f;
}

// ---------------------------------------------------------------------------
// Main kernel. Block = 8x16 spatial tile (one n) x 32 oc. 256 threads = 4 waves.
// Wave w: parity p = w&1, oc group og = w>>1. Lane = one output position of
// that parity (checkerboard), so W~ addresses are wave-uniform.
// ---------------------------------------------------------------------------
template<int P>
__device__ __forceinline__ void aeg_body(
    const float* __restrict__ Wt, const float (*xs)[10][18],
    int oc0, int r, int c, int n, int gi, int gj, float* __restrict__ out)
{
    float acc[16];
    #pragma unroll
    for (int o = 0; o < 16; ++o) acc[o] = 0.f;

    for (int ic = 0; ic < C_IN; ++ic) {
        float xv[9];
        #pragma unroll
        for (int dh = 0; dh < 3; ++dh)
            #pragma unroll
            for (int dw = 0; dw < 3; ++dw)
                xv[dh * 3 + dw] = xs[ic][r + dh][c + dw];

        // X~_k: suffix products of odd-step x's; even steps multiply own x.
        float Xt[9];
        float Ox = 1.f;
        #pragma unroll
        for (int k = 8; k >= 0; --k) {
            if (((P + k) & 1) == 1) { Ox *= xv[k]; Xt[k] = Ox; }
            else                    { Xt[k] = xv[k] * Ox; }
        }

        const float* wr = Wt + ((P * C_IN + ic) * C_OUT + oc0) * 12;
        #pragma unroll
        for (int o = 0; o < 16; ++o) {
            float s = acc[o];
            #pragma unroll
            for (int k = 0; k < 9; ++k)
                s = fmaf(Xt[k], wr[o * 12 + k], s);
            acc[o] = s;
        }
    }

    float* op = out + ((n * C_OUT + oc0) * HH + gi) * WW + gj;
    #pragma unroll
    for (int o = 0; o < 16; ++o)
        op[o * (HH * WW)] = acc[o];
}

__global__ __launch_bounds__(256) void aeg_main(
    const float* __restrict__ x, const float* __restrict__ Wt,
    float* __restrict__ out)
{
    __shared__ float xs[C_IN][10][18];

    int bid = blockIdx.x;
    int oh = bid & 1;          // oc half (0..1)
    int tc = (bid >> 1) & 3;   // col tile (0..3), 16 cols each
    int tr = (bid >> 3) & 7;   // row tile (0..7), 8 rows each
    int n  = bid >> 6;         // batch (0..7)
    int tid = threadIdx.x;

    // Stage padded x tile: rows tr*8-1..tr*8+8, cols tc*16-1..tc*16+16
    for (int ll = tid; ll < C_IN * 10 * 18; ll += 256) {
        int ic  = ll / 180;
        int rem = ll - ic * 180;
        int rr  = rem / 18;
        int cc  = rem - rr * 18;
        int gi  = tr * 8 + rr - 1;
        int gj  = tc * 16 + cc - 1;
        float v = 0.f;
        if ((unsigned)gi < 64u && (unsigned)gj < 64u)
            v = x[((n * C_IN + ic) * HH + gi) * WW + gj];
        xs[ic][rr][cc] = v;
    }
    __syncthreads();

    int wv = __builtin_amdgcn_readfirstlane(tid >> 6); // wave id 0..3
    int p  = wv & 1;
    int og = wv >> 1;                                  // 0..1
    int oc0 = oh * 32 + og * 16;

    int l = tid & 63;
    int r = l >> 3;                                    // 0..7
    int c = ((l & 7) << 1) + ((p + r) & 1);            // checkerboard col
    int gi = tr * 8 + r, gj = tc * 16 + c;

    if (p == 0) aeg_body<0>(Wt, xs, oc0, r, c, n, gi, gj, out);
    else        aeg_body<1>(Wt, xs, oc0, r, c, n, gi, gj, out);
}

extern "C" void kernel_launch(void* const* d_in, const int* in_sizes, int n_in,
                              void* d_out, int out_size, void* d_ws, size_t ws_size,
                              hipStream_t stream) {
    const float* x = (const float*)d_in[0];
    const float* w = (const float*)d_in[1];
    float* out = (float*)d_out;
    float* Wt  = (float*)d_ws;   // needs 2*32*64*12*4 = 196,608 bytes

    wprod_kernel<<<16, 256, 0, stream>>>(w, Wt);
    aeg_main<<<512, 256, 0, stream>>>(x, Wt, out);
}

// Round 2
// 63.720 us; speedup vs baseline: 1.1428x; 1.1428x over previous
//
#include <hip/hip_runtime.h>

#define C_IN  32
#define C_OUT 64
#define HH    64
#define WW    64
#define IC_HALF 16

// ---------------------------------------------------------------------------
// Weight-product precompute: Wt[p][ic][oc][12] (9 used + 3 pad)
// W~_k = Ew(k) * (w_k if (p+k) odd), Ew(k) = prod_{j>=k, (p+j) even} w_j
// ---------------------------------------------------------------------------
__global__ void wprod_kernel(const float* __restrict__ w, float* __restrict__ Wt) {
    int t = blockIdx.x * 256 + threadIdx.x;
    if (t >= 2 * C_IN * C_OUT) return;
    int oc = t & 63;
    int ic = (t >> 6) & 31;
    int p  = t >> 11;
    const float* wp = w + (oc * C_IN + ic) * 9;
    float W[9];
    float Ew = 1.f;
    #pragma unroll
    for (int k = 8; k >= 0; --k) {
        float wk = wp[k];
        if (((p + k) & 1) == 0) { Ew *= wk; W[k] = Ew; }
        else                    { W[k] = wk * Ew; }
    }
    float* dst = Wt + ((p * C_IN + ic) * C_OUT + oc) * 12;
    #pragma unroll
    for (int k = 0; k < 9; ++k) dst[k] = W[k];
    dst[9] = 0.f; dst[10] = 0.f; dst[11] = 0.f;
}

#if defined(__has_builtin) && __has_builtin(__builtin_amdgcn_global_atomic_fadd_f32)
#define ATOMIC_FADD(p, v) unsafeAtomicAdd((p), (v))
#else
#define ATOMIC_FADD(p, v) atomicAdd((p), (v))
#endif

// ---------------------------------------------------------------------------
// Main kernel. Block = 8x16 spatial tile (one n) x 32 oc x 16 ic (half).
// 256 threads = 4 waves. Wave w: parity p = w&1, oc group og = w>>1.
// Lane = one output position of that parity (checkerboard), so W~ addresses
// are wave-uniform (scalar loads). Two blocks (ic halves) atomically combine.
// ---------------------------------------------------------------------------
template<int P>
__device__ __forceinline__ void aeg_body(
    const float* __restrict__ Wt, const float (*xs)[10][19],
    int oc0, int icg0, int r, int c, int n, int gi, int gj,
    float* __restrict__ out)
{
    float acc[16];
    #pragma unroll
    for (int o = 0; o < 16; ++o) acc[o] = 0.f;

    for (int ic = 0; ic < IC_HALF; ++ic) {
        float xv[9];
        #pragma unroll
        for (int dh = 0; dh < 3; ++dh)
            #pragma unroll
            for (int dw = 0; dw < 3; ++dw)
                xv[dh * 3 + dw] = xs[ic][r + dh][c + dw];

        // X~_k: suffix products of odd-step x's; even steps multiply own x.
        float Xt[9];
        float Ox = 1.f;
        #pragma unroll
        for (int k = 8; k >= 0; --k) {
            if (((P + k) & 1) == 1) { Ox *= xv[k]; Xt[k] = Ox; }
            else                    { Xt[k] = xv[k] * Ox; }
        }

        const float* wr = Wt + ((P * C_IN + (icg0 + ic)) * C_OUT + oc0) * 12;
        #pragma unroll
        for (int o = 0; o < 16; ++o) {
            float s = acc[o];
            #pragma unroll
            for (int k = 0; k < 9; ++k)
                s = fmaf(Xt[k], wr[o * 12 + k], s);
            acc[o] = s;
        }
    }

    float* op = out + ((n * C_OUT + oc0) * HH + gi) * WW + gj;
    #pragma unroll
    for (int o = 0; o < 16; ++o)
        ATOMIC_FADD(op + o * (HH * WW), acc[o]);
}

__global__ __launch_bounds__(256) void aeg_main(
    const float* __restrict__ x, const float* __restrict__ Wt,
    float* __restrict__ out)
{
    __shared__ float xs[IC_HALF][10][19];

    int bid = blockIdx.x;
    int oh = bid & 1;          // oc half (0..1)
    int tc = (bid >> 1) & 3;   // col tile (0..3), 16 cols each
    int tr = (bid >> 3) & 7;   // row tile (0..7), 8 rows each
    int ih = (bid >> 6) & 1;   // ic half (0..1)
    int n  = bid >> 7;         // batch (0..7)
    int tid = threadIdx.x;

    // Stage padded x tile for our 16-ic half:
    // rows tr*8-1..tr*8+8, cols tc*16-1..tc*16+16
    for (int ll = tid; ll < IC_HALF * 10 * 19; ll += 256) {
        int ic  = ll / 190;
        int rem = ll - ic * 190;
        int rr  = rem / 19;
        int cc  = rem - rr * 19;
        float v = 0.f;
        if (cc < 18) {
            int gi = tr * 8 + rr - 1;
            int gj = tc * 16 + cc - 1;
            if ((unsigned)gi < 64u && (unsigned)gj < 64u)
                v = x[((n * C_IN + ih * IC_HALF + ic) * HH + gi) * WW + gj];
        }
        xs[ic][rr][cc] = v;
    }
    __syncthreads();

    int wv = __builtin_amdgcn_readfirstlane(tid >> 6); // wave id 0..3
    int p  = wv & 1;
    int og = wv >> 1;                                  // 0..1
    int oc0 = oh * 32 + og * 16;
    int icg0 = ih * IC_HALF;

    int l = tid & 63;
    int r = l >> 3;                                    // 0..7
    int c = ((l & 7) << 1) + ((p + r) & 1);            // checkerboard col
    int gi = tr * 8 + r, gj = tc * 16 + c;

    if (p == 0) aeg_body<0>(Wt, xs, oc0, icg0, r, c, n, gi, gj, out);
    else        aeg_body<1>(Wt, xs, oc0, icg0, r, c, n, gi, gj, out);
}

extern "C" void kernel_launch(void* const* d_in, const int* in_sizes, int n_in,
                              void* d_out, int out_size, void* d_ws, size_t ws_size,
                              hipStream_t stream) {
    const float* x = (const float*)d_in[0];
    const float* w = (const float*)d_in[1];
    float* out = (float*)d_out;
    float* Wt  = (float*)d_ws;   // needs 2*32*64*12*4 = 196,608 bytes

    hipMemsetAsync(out, 0, (size_t)out_size * sizeof(float), stream);
    wprod_kernel<<<16, 256, 0, stream>>>(w, Wt);
    aeg_main<<<1024, 256, 0, stream>>>(x, Wt, out);
}